// Round 1
// baseline (316.137 us; speedup 1.0000x reference)
//
#include <hip/hip_runtime.h>

// PreHTSK fused: firing-levels -> softmax -> analytic LayerNorm -> folded GEMM.
// feats is NEVER materialized: feats[b, r*256+i] = X[b,i]*frs[b,r], tail = frs.
// LN moments closed-form via sum(frs)=1: mu=(Sx+1)/D, E[f^2]=Q*(Sx2+1)/D.
// out[b,o] = rstd*S - mu*rstd*G[o] + Bb[o],  S = sum_d f[b,d]*gamma[d]*W[o,d].

#define B_    2048
#define IN_   256
#define NR_   128
#define OUT_  64
#define D_    32896   // (IN_+1)*NR_
#define XP_   32768   // IN_*NR_
#define KSPLIT 16
#define RPS   8       // NR_/KSPLIT rules per split
#define BM    128
#define LDSP  68      // padded LDS stride (floats), 16B-aligned rows

// ---------- per-rule constants: scale = H/sig^2+EPS, scale*c, Cr = sum scale*c^2
__global__ __launch_bounds__(256) void prep_rules(const float* __restrict__ centers,
                                                  const float* __restrict__ sigmas,
                                                  float* __restrict__ scaleA,
                                                  float* __restrict__ scB,
                                                  float* __restrict__ Cr) {
  int r = blockIdx.x;    // 0..127
  int i = threadIdx.x;   // 0..255
  __shared__ float red[256];
  float sg = sigmas[i * NR_ + r];
  float c  = centers[i * NR_ + r];
  float s  = 0.5f / (sg * sg) + 1e-8f;   // H=0.5, EPS=1e-8
  scaleA[i * NR_ + r] = s;
  scB[i * NR_ + r]    = s * c;
  red[i] = s * c * c;
  __syncthreads();
  for (int st = 128; st > 0; st >>= 1) {
    if (i < st) red[i] += red[i + st];
    __syncthreads();
  }
  if (i == 0) Cr[r] = red[0];
}

// ---------- G[o] = sum_d gamma*W, Bb[o] = sum_d beta*W + bias
__global__ __launch_bounds__(256) void prep_w(const float* __restrict__ W,
                                              const float* __restrict__ gamma,
                                              const float* __restrict__ beta,
                                              const float* __restrict__ bias,
                                              float* __restrict__ G,
                                              float* __restrict__ Bb) {
  int o = blockIdx.x, t = threadIdx.x;
  __shared__ float redg[256], redb[256];
  float g = 0.f, bb = 0.f;
  for (int d = t; d < D_; d += 256) {
    float w = W[(size_t)o * D_ + d];
    g  += w * gamma[d];
    bb += w * beta[d];
  }
  redg[t] = g; redb[t] = bb;
  __syncthreads();
  for (int st = 128; st > 0; st >>= 1) {
    if (t < st) { redg[t] += redg[t + st]; redb[t] += redb[t + st]; }
    __syncthreads();
  }
  if (t == 0) { G[o] = redg[0]; Bb[o] = redb[0] + bias[o]; }
}

// ---------- per-row firing levels + softmax + LN stats
__global__ __launch_bounds__(128) void frs_kernel(const float* __restrict__ X,
                                                  const float* __restrict__ scaleA,
                                                  const float* __restrict__ scB,
                                                  const float* __restrict__ Cr,
                                                  float* __restrict__ frs,
                                                  float* __restrict__ rstdO,
                                                  float* __restrict__ murO) {
  int b = blockIdx.x, t = threadIdx.x;   // t = rule index
  __shared__ float Xs[IN_], X2s[IN_], red[128];
  float x1 = X[b * IN_ + t], x2 = X[b * IN_ + 128 + t];
  Xs[t] = x1; Xs[t + 128] = x2;
  X2s[t] = x1 * x1; X2s[t + 128] = x2 * x2;
  float sxp  = x1 + x2;
  float sx2p = x1 * x1 + x2 * x2;
  __syncthreads();
  float acc1 = 0.f, acc2 = 0.f;
#pragma unroll 8
  for (int i = 0; i < IN_; i++) {
    acc1 = fmaf(X2s[i], scaleA[i * NR_ + t], acc1);
    acc2 = fmaf(Xs[i],  scB[i * NR_ + t],  acc2);
  }
  float pre = -(acc1 - 2.f * acc2 + Cr[t]) * (1.f / (float)IN_);
  // block max
  red[t] = pre; __syncthreads();
  for (int st = 64; st > 0; st >>= 1) { if (t < st) red[t] = fmaxf(red[t], red[t + st]); __syncthreads(); }
  float M = red[0]; __syncthreads();
  float e = expf(pre - M);
  red[t] = e; __syncthreads();
  for (int st = 64; st > 0; st >>= 1) { if (t < st) red[t] += red[t + st]; __syncthreads(); }
  float Ssum = red[0]; __syncthreads();
  float fr = e / Ssum;
  frs[b * NR_ + t] = fr;
  red[t] = fr * fr; __syncthreads();
  for (int st = 64; st > 0; st >>= 1) { if (t < st) red[t] += red[t + st]; __syncthreads(); }
  float Q = red[0]; __syncthreads();
  red[t] = sxp; __syncthreads();
  for (int st = 64; st > 0; st >>= 1) { if (t < st) red[t] += red[t + st]; __syncthreads(); }
  float Sx = red[0]; __syncthreads();
  red[t] = sx2p; __syncthreads();
  for (int st = 64; st > 0; st >>= 1) { if (t < st) red[t] += red[t + st]; __syncthreads(); }
  if (t == 0) {
    float Sx2 = red[0];
    float mu  = (Sx + 1.f) / (float)D_;
    float msq = Q * (Sx2 + 1.f) / (float)D_;
    float var = msq - mu * mu;
    float rs  = rsqrtf(var + 1e-5f);
    rstdO[b] = rs;
    murO[b]  = mu * rs;
  }
}

// ---------- fused GEMM: S[b,o] = sum_d a[b,d]*gamma[d]*W[o,d], a generated on the fly.
// Grid: (16 b-tiles) x (KSPLIT rule-groups). Each block: 128 b-rows x 64 o-cols,
// K range = RPS*256 (+RPS concat tail). Partials to Spart[ks][b][o].
__global__ __launch_bounds__(256) void gemm_kernel(const float* __restrict__ X,
                                                   const float* __restrict__ W,
                                                   const float* __restrict__ gamma,
                                                   const float* __restrict__ frs,
                                                   float* __restrict__ Spart) {
  int bt = blockIdx.x;   // 0..15
  int ks = blockIdx.y;   // 0..KSPLIT-1
  int tid = threadIdx.x;
  __shared__ float As[BM][LDSP];     // [b][k], k contiguous
  __shared__ float Bs[64][LDSP];     // [k][o], o contiguous
  __shared__ float frs_s[BM][RPS];
  __shared__ float W2s[RPS][64];
  int rBase = ks * RPS;

  for (int idx = tid; idx < BM * RPS; idx += 256) {
    int bb = idx >> 3, rr = idx & (RPS - 1);
    frs_s[bb][rr] = frs[(bt * BM + bb) * NR_ + rBase + rr];
  }
  for (int idx = tid; idx < RPS * 64; idx += 256) {
    int rr = idx >> 6, oo = idx & 63;
    int d = XP_ + rBase + rr;
    W2s[rr][oo] = W[(size_t)oo * D_ + d] * gamma[d];
  }

  float acc[8][4] = {};
  int c    = tid & 63;    // k-column for staging
  int row4 = tid >> 6;    // 0..3
  int tb   = tid >> 4;    // 0..15 -> b rows tb + 16*i
  int to   = tid & 15;    // o quad
  __syncthreads();

  for (int step = 0; step < RPS * 4; step++) {
    int rr = step >> 2;                 // rule within split
    int i0 = (step & 3) * 64;
    int dd = (rBase + rr) * IN_ + i0 + c;  // global feature index
    float gk = gamma[dd];
    // A tile: As[bb][c] = frs[bb,rr] * X[bb, i0+c]   (writes conflict-free)
    for (int bb = row4; bb < BM; bb += 4)
      As[bb][c] = frs_s[bb][rr] * X[(size_t)(bt * BM + bb) * IN_ + i0 + c];
    // B tile: Bs[c][oo] = gamma*W  (8-way write conflict, negligible vs compute)
    for (int oo = row4; oo < 64; oo += 4)
      Bs[c][oo] = W[(size_t)oo * D_ + dd] * gk;
    __syncthreads();
#pragma unroll
    for (int k = 0; k < 64; k += 4) {
      float4 b0 = *(const float4*)&Bs[k + 0][to * 4];
      float4 b1 = *(const float4*)&Bs[k + 1][to * 4];
      float4 b2 = *(const float4*)&Bs[k + 2][to * 4];
      float4 b3 = *(const float4*)&Bs[k + 3][to * 4];
#pragma unroll
      for (int i = 0; i < 8; i++) {
        float4 a = *(const float4*)&As[tb + 16 * i][k];
        acc[i][0] = fmaf(a.x, b0.x, fmaf(a.y, b1.x, fmaf(a.z, b2.x, fmaf(a.w, b3.x, acc[i][0]))));
        acc[i][1] = fmaf(a.x, b0.y, fmaf(a.y, b1.y, fmaf(a.z, b2.y, fmaf(a.w, b3.y, acc[i][1]))));
        acc[i][2] = fmaf(a.x, b0.z, fmaf(a.y, b1.z, fmaf(a.z, b2.z, fmaf(a.w, b3.z, acc[i][2]))));
        acc[i][3] = fmaf(a.x, b0.w, fmaf(a.y, b1.w, fmaf(a.z, b2.w, fmaf(a.w, b3.w, acc[i][3]))));
      }
    }
    __syncthreads();
  }

  // concat tail: S += frs[b,r]*gamma*W[o, XP_+r]
#pragma unroll
  for (int rr = 0; rr < RPS; rr++) {
#pragma unroll
    for (int i = 0; i < 8; i++) {
      float f = frs_s[tb + 16 * i][rr];
      acc[i][0] = fmaf(f, W2s[rr][to * 4 + 0], acc[i][0]);
      acc[i][1] = fmaf(f, W2s[rr][to * 4 + 1], acc[i][1]);
      acc[i][2] = fmaf(f, W2s[rr][to * 4 + 2], acc[i][2]);
      acc[i][3] = fmaf(f, W2s[rr][to * 4 + 3], acc[i][3]);
    }
  }

#pragma unroll
  for (int i = 0; i < 8; i++) {
    int brow = bt * BM + tb + 16 * i;
#pragma unroll
    for (int j = 0; j < 4; j++)
      Spart[((size_t)ks * B_ + brow) * OUT_ + to * 4 + j] = acc[i][j];
  }
}

// ---------- epilogue: sum K-split partials, apply LN scale + bias terms
__global__ __launch_bounds__(256) void epilogue_kernel(const float* __restrict__ Spart,
                                                       const float* __restrict__ rstd,
                                                       const float* __restrict__ mur,
                                                       const float* __restrict__ G,
                                                       const float* __restrict__ Bb,
                                                       float* __restrict__ out) {
  int idx = blockIdx.x * 256 + threadIdx.x;   // 0..B_*OUT_-1
  int b = idx >> 6, o = idx & 63;
  float s = 0.f;
#pragma unroll
  for (int ks = 0; ks < KSPLIT; ks++)
    s += Spart[((size_t)ks * B_ + b) * OUT_ + o];
  out[idx] = rstd[b] * s - mur[b] * G[o] + Bb[o];
}

extern "C" void kernel_launch(void* const* d_in, const int* in_sizes, int n_in,
                              void* d_out, int out_size, void* d_ws, size_t ws_size,
                              hipStream_t stream) {
  const float* X       = (const float*)d_in[0];
  const float* centers = (const float*)d_in[1];
  const float* sigmas  = (const float*)d_in[2];
  const float* gamma   = (const float*)d_in[3];
  const float* beta    = (const float*)d_in[4];
  const float* W       = (const float*)d_in[5];
  const float* bias    = (const float*)d_in[6];
  float* out = (float*)d_out;

  float* ws     = (float*)d_ws;
  float* scaleA = ws;                    // 32768
  float* scB    = scaleA + XP_;          // 32768
  float* Cr     = scB + XP_;             // 128
  float* G      = Cr + NR_;              // 64
  float* Bb     = G + OUT_;              // 64
  float* frs    = Bb + OUT_;             // B_*NR_
  float* rstd   = frs + B_ * NR_;        // B_
  float* mur    = rstd + B_;             // B_
  float* Spart  = mur + B_;              // KSPLIT*B_*OUT_  (~8 MB)

  hipLaunchKernelGGL(prep_rules, dim3(NR_), dim3(IN_), 0, stream,
                     centers, sigmas, scaleA, scB, Cr);
  hipLaunchKernelGGL(prep_w, dim3(OUT_), dim3(256), 0, stream,
                     W, gamma, beta, bias, G, Bb);
  hipLaunchKernelGGL(frs_kernel, dim3(B_), dim3(128), 0, stream,
                     X, scaleA, scB, Cr, frs, rstd, mur);
  hipLaunchKernelGGL(gemm_kernel, dim3(16, KSPLIT), dim3(256), 0, stream,
                     X, W, gamma, frs, Spart);
  hipLaunchKernelGGL(epilogue_kernel, dim3((B_ * OUT_) / 256), dim3(256), 0, stream,
                     Spart, rstd, mur, G, Bb, out);
}

// Round 2
// 154.485 us; speedup vs baseline: 2.0464x; 2.0464x over previous
//
#include <hip/hip_runtime.h>

// PreHTSK fused, MFMA edition.
// out[b,o] = rstd*(S + T) - mu*rstd*G[o] + Bb[o]
//   S = sum_r frs[b,r] * sum_i X[b,i]*gamma[r*256+i]*W[o, r*256+i]   (MFMA, A=X in regs)
//   T = sum_r frs[b,r] * Wtail[r][o]                                  (epilogue)
// LN moments closed-form: mu=(Sx+1)/D, E[f^2]=Q*(Sx2+1)/D, Q=sum frs^2.

#define B_    2048
#define IN_   256
#define NR_   128
#define OUT_  64
#define D_    32896
#define XP_   32768
#define KSPLIT 16   // rule-groups -> gemm grid.y ; 8 rules per block

typedef short s16x8 __attribute__((ext_vector_type(8)));
typedef float f32x4 __attribute__((ext_vector_type(4)));

__device__ __forceinline__ unsigned short bfc(float f) {
  union { float f; unsigned int u; } v; v.f = f;
  unsigned int r = (v.u + 0x7fffu + ((v.u >> 16) & 1u)) >> 16;  // RNE
  return (unsigned short)r;
}

// ---------- per-rule constants
__global__ __launch_bounds__(256) void prep_rules(const float* __restrict__ centers,
                                                  const float* __restrict__ sigmas,
                                                  float* __restrict__ scaleA,
                                                  float* __restrict__ scB,
                                                  float* __restrict__ Cr) {
  int r = blockIdx.x;    // 0..127
  int i = threadIdx.x;   // 0..255
  __shared__ float red[256];
  float sg = sigmas[i * NR_ + r];
  float c  = centers[i * NR_ + r];
  float s  = 0.5f / (sg * sg) + 1e-8f;
  scaleA[i * NR_ + r] = s;
  scB[i * NR_ + r]    = s * c;
  red[i] = s * c * c;
  __syncthreads();
  for (int st = 128; st > 0; st >>= 1) {
    if (i < st) red[i] += red[i + st];
    __syncthreads();
  }
  if (i == 0) Cr[r] = red[0];
}

// ---------- G[o], Bb[o], Wtail[r][o]
__global__ __launch_bounds__(256) void prep_w(const float* __restrict__ W,
                                              const float* __restrict__ gamma,
                                              const float* __restrict__ beta,
                                              const float* __restrict__ bias,
                                              float* __restrict__ G,
                                              float* __restrict__ Bb,
                                              float* __restrict__ Wtail) {
  int o = blockIdx.x, t = threadIdx.x;
  __shared__ float redg[256], redb[256];
  if (t < NR_) {
    int d = XP_ + t;
    Wtail[t * OUT_ + o] = W[(size_t)o * D_ + d] * gamma[d];
  }
  float g = 0.f, bb = 0.f;
  for (int d = t; d < D_; d += 256) {
    float w = W[(size_t)o * D_ + d];
    g  += w * gamma[d];
    bb += w * beta[d];
  }
  redg[t] = g; redb[t] = bb;
  __syncthreads();
  for (int st = 128; st > 0; st >>= 1) {
    if (t < st) { redg[t] += redg[t + st]; redb[t] += redb[t + st]; }
    __syncthreads();
  }
  if (t == 0) { G[o] = redg[0]; Bb[o] = redb[0] + bias[o]; }
}

// ---------- pack gamma*W into MFMA B-fragment order, bf16
// Bpack[r][kc(8)][ct(4)][lane(64)][j(8)] ; element (k=kc*32+(lane>>4)*8+j, o=ct*16+(lane&15))
__global__ __launch_bounds__(64) void prep_bpack(const float* __restrict__ W,
                                                 const float* __restrict__ gamma,
                                                 unsigned short* __restrict__ Bpack) {
  int kc = blockIdx.x;   // 0..7
  int r  = blockIdx.y;   // 0..127
  int lane = threadIdx.x;
  int d0 = r * 256 + kc * 32 + (lane >> 4) * 8;
  float4 g0 = *(const float4*)&gamma[d0];
  float4 g1 = *(const float4*)&gamma[d0 + 4];
#pragma unroll
  for (int ct = 0; ct < 4; ct++) {
    int o = ct * 16 + (lane & 15);
    const float* wp = &W[(size_t)o * D_ + d0];
    float4 w0 = *(const float4*)wp;
    float4 w1 = *(const float4*)(wp + 4);
    unsigned int u[4];
    u[0] = bfc(w0.x * g0.x) | ((unsigned int)bfc(w0.y * g0.y) << 16);
    u[1] = bfc(w0.z * g0.z) | ((unsigned int)bfc(w0.w * g0.w) << 16);
    u[2] = bfc(w1.x * g1.x) | ((unsigned int)bfc(w1.y * g1.y) << 16);
    u[3] = bfc(w1.z * g1.z) | ((unsigned int)bfc(w1.w * g1.w) << 16);
    uint4 pk = make_uint4(u[0], u[1], u[2], u[3]);
    *(uint4*)&Bpack[((size_t)((r * 8 + kc) * 4 + ct) * 64 + lane) * 8] = pk;
  }
}

// ---------- firing levels + softmax + LN stats + X->bf16  (8 rows/block)
__global__ __launch_bounds__(512) void frs_kernel(const float* __restrict__ X,
                                                  const float* __restrict__ scaleA,
                                                  const float* __restrict__ scB,
                                                  const float* __restrict__ Cr,
                                                  float* __restrict__ frs,
                                                  float* __restrict__ rstdO,
                                                  float* __restrict__ murO,
                                                  unsigned short* __restrict__ Xbf) {
  int bt = blockIdx.x;           // 256 blocks
  int tid = threadIdx.x;         // 512
  __shared__ float Xs[8][256];
  __shared__ float pre[4][8][128];
  int b0 = bt * 8;
  {
    int row = tid >> 6, c4 = (tid & 63) * 4;
    float4 x = *(const float4*)&X[(size_t)(b0 + row) * 256 + c4];
    *(float4*)&Xs[row][c4] = x;
    uint2 p;
    p.x = bfc(x.x) | ((unsigned int)bfc(x.y) << 16);
    p.y = bfc(x.z) | ((unsigned int)bfc(x.w) << 16);
    *(uint2*)&Xbf[(size_t)(b0 + row) * 256 + c4] = p;
  }
  __syncthreads();
  int r = tid & 127, h = tid >> 7;   // h = 0..3 (i-quarter)
  float acc[8] = {0.f,0.f,0.f,0.f,0.f,0.f,0.f,0.f};
  int i0 = h * 64;
#pragma unroll 4
  for (int i = i0; i < i0 + 64; i++) {
    float sa   = scaleA[i * 128 + r];
    float msb2 = -2.f * scB[i * 128 + r];
#pragma unroll
    for (int row = 0; row < 8; row++) {
      float x = Xs[row][i];
      acc[row] = fmaf(x, fmaf(x, sa, msb2), acc[row]);
    }
  }
#pragma unroll
  for (int row = 0; row < 8; row++) pre[h][row][r] = acc[row];
  __syncthreads();
  // wave w handles row w
  int wv = tid >> 6, lane = tid & 63;
  float v0 = pre[0][wv][lane]      + pre[1][wv][lane]      + pre[2][wv][lane]      + pre[3][wv][lane]      + Cr[lane];
  float v1 = pre[0][wv][lane + 64] + pre[1][wv][lane + 64] + pre[2][wv][lane + 64] + pre[3][wv][lane + 64] + Cr[lane + 64];
  v0 *= -(1.f / 256.f);
  v1 *= -(1.f / 256.f);
  float m = fmaxf(v0, v1);
  for (int st = 32; st; st >>= 1) m = fmaxf(m, __shfl_xor(m, st));
  float e0 = __expf(v0 - m), e1 = __expf(v1 - m);
  float s = e0 + e1;
  for (int st = 32; st; st >>= 1) s += __shfl_xor(s, st);
  float invs = 1.f / s;
  float f0 = e0 * invs, f1 = e1 * invs;
  int b = b0 + wv;
  frs[(size_t)b * 128 + lane]      = f0;
  frs[(size_t)b * 128 + 64 + lane] = f1;
  float q = f0 * f0 + f1 * f1;
  for (int st = 32; st; st >>= 1) q += __shfl_xor(q, st);
  float sx = 0.f, sx2 = 0.f;
#pragma unroll
  for (int j = 0; j < 4; j++) {
    float x = Xs[wv][lane * 4 + j];
    sx += x; sx2 = fmaf(x, x, sx2);
  }
  for (int st = 32; st; st >>= 1) { sx += __shfl_xor(sx, st); sx2 += __shfl_xor(sx2, st); }
  if (lane == 0) {
    float mu  = (sx + 1.f) / (float)D_;
    float msq = q * (sx2 + 1.f) / (float)D_;
    float var = msq - mu * mu;
    float rs  = rsqrtf(var + 1e-5f);
    rstdO[b] = rs;
    murO[b]  = mu * rs;
  }
}

// ---------- MFMA GEMM: grid (16 bt, 16 ks), 512 threads (8 waves)
// block tile: 128 rows x 64 cols, 8 rules. wave (wr=w&3, wc=w>>2): rows wr*32+[0,32), cols wc*32+[0,32).
__global__ __launch_bounds__(512) void gemm_kernel(const unsigned short* __restrict__ Xbf,
                                                   const unsigned short* __restrict__ Bpack,
                                                   const float* __restrict__ frs,
                                                   float* __restrict__ Spart) {
  int bt = blockIdx.x;
  int ks = blockIdx.y;
  int tid = threadIdx.x;
  int lane = tid & 63;
  int w = tid >> 6, wr = w & 3, wc = w >> 2;
  __shared__ unsigned short Blds[2][16384];   // 2 x 32KB
  __shared__ float frs_s[128][8];

  for (int idx = tid; idx < 128 * 8; idx += 512) {
    int row = idx >> 3, rr = idx & 7;
    frs_s[row][rr] = frs[(size_t)(bt * 128 + row) * 128 + ks * 8 + rr];
  }

  // X fragments in registers: xf[rf][kc], reused across all rules
  s16x8 xf[2][8];
  int browbase = bt * 128 + wr * 32;
#pragma unroll
  for (int rf = 0; rf < 2; rf++) {
    const unsigned short* xp = Xbf + (size_t)(browbase + rf * 16 + (lane & 15)) * 256 + (lane >> 4) * 8;
#pragma unroll
    for (int kc = 0; kc < 8; kc++)
      xf[rf][kc] = *(const s16x8*)(xp + kc * 32);
  }

  // stage rule 0
  const s16x8* bsrc = (const s16x8*)Bpack + (size_t)(ks * 8) * 2048;
  {
    s16x8* dst = (s16x8*)&Blds[0][0];
#pragma unroll
    for (int p = 0; p < 4; p++) dst[tid + p * 512] = bsrc[tid + p * 512];
  }
  __syncthreads();

  f32x4 S00 = {0.f,0.f,0.f,0.f}, S01 = S00, S10 = S00, S11 = S00;
  f32x4 P00 = S00, P01 = S00, P10 = S00, P11 = S00;

  for (int rr = 0; rr < 8; rr++) {
    s16x8 stg0, stg1, stg2, stg3;
    if (rr < 7) {               // T14: issue next-rule loads early
      const s16x8* src = bsrc + (size_t)(rr + 1) * 2048;
      stg0 = src[tid]; stg1 = src[tid + 512]; stg2 = src[tid + 1024]; stg3 = src[tid + 1536];
    }
    const unsigned short* bb = &Blds[rr & 1][0];
#pragma unroll
    for (int kc = 0; kc < 8; kc++) {
      s16x8 bf0 = *(const s16x8*)(bb + (size_t)((kc * 4 + wc * 2 + 0) * 64 + lane) * 8);
      s16x8 bf1 = *(const s16x8*)(bb + (size_t)((kc * 4 + wc * 2 + 1) * 64 + lane) * 8);
      P00 = __builtin_amdgcn_mfma_f32_16x16x32_bf16(xf[0][kc], bf0, P00, 0, 0, 0);
      P01 = __builtin_amdgcn_mfma_f32_16x16x32_bf16(xf[0][kc], bf1, P01, 0, 0, 0);
      P10 = __builtin_amdgcn_mfma_f32_16x16x32_bf16(xf[1][kc], bf0, P10, 0, 0, 0);
      P11 = __builtin_amdgcn_mfma_f32_16x16x32_bf16(xf[1][kc], bf1, P11, 0, 0, 0);
    }
    // fold P -> S with f32 frs, reset P
#pragma unroll
    for (int q = 0; q < 4; q++) {
      float fv0 = frs_s[wr * 32 + 0  + (lane >> 4) * 4 + q][rr];
      float fv1 = frs_s[wr * 32 + 16 + (lane >> 4) * 4 + q][rr];
      S00[q] += fv0 * P00[q];  S01[q] += fv0 * P01[q];
      S10[q] += fv1 * P10[q];  S11[q] += fv1 * P11[q];
      P00[q] = 0.f; P01[q] = 0.f; P10[q] = 0.f; P11[q] = 0.f;
    }
    if (rr < 7) {
      s16x8* dst = (s16x8*)&Blds[(rr + 1) & 1][0];
      dst[tid] = stg0; dst[tid + 512] = stg1; dst[tid + 1024] = stg2; dst[tid + 1536] = stg3;
    }
    __syncthreads();
  }

  // store partials
#pragma unroll
  for (int q = 0; q < 4; q++) {
    int row0 = browbase + 0  + (lane >> 4) * 4 + q;
    int row1 = browbase + 16 + (lane >> 4) * 4 + q;
    int o0 = wc * 32 + (lane & 15);
    Spart[((size_t)ks * B_ + row0) * OUT_ + o0]      = S00[q];
    Spart[((size_t)ks * B_ + row0) * OUT_ + o0 + 16] = S01[q];
    Spart[((size_t)ks * B_ + row1) * OUT_ + o0]      = S10[q];
    Spart[((size_t)ks * B_ + row1) * OUT_ + o0 + 16] = S11[q];
  }
}

// ---------- epilogue: sum partials + tail GEMV + LN affine
__global__ __launch_bounds__(256) void epilogue_kernel(const float* __restrict__ Spart,
                                                       const float* __restrict__ frs,
                                                       const float* __restrict__ Wtail,
                                                       const float* __restrict__ rstd,
                                                       const float* __restrict__ mur,
                                                       const float* __restrict__ G,
                                                       const float* __restrict__ Bb,
                                                       float* __restrict__ out) {
  int bt = blockIdx.x;        // 256 blocks, 8 rows each
  int tid = threadIdx.x;
  __shared__ float Wt[128 * 64];    // 32KB
  __shared__ float fr_s[8][128];
  for (int idx = tid; idx < 128 * 64; idx += 256) Wt[idx] = Wtail[idx];
  for (int idx = tid; idx < 8 * 128; idx += 256) {
    int row = idx >> 7, r = idx & 127;
    fr_s[row][r] = frs[(size_t)(bt * 8 + row) * 128 + r];
  }
  __syncthreads();
  int o = tid & 63, rg = tid >> 6;
  for (int rw = rg; rw < 8; rw += 4) {
    int b = bt * 8 + rw;
    float s = 0.f;
#pragma unroll
    for (int ksi = 0; ksi < KSPLIT; ksi++)
      s += Spart[((size_t)ksi * B_ + b) * OUT_ + o];
    float t = 0.f;
#pragma unroll 8
    for (int r = 0; r < 128; r++)
      t = fmaf(fr_s[rw][r], Wt[r * 64 + o], t);
    out[(size_t)b * OUT_ + o] = rstd[b] * (s + t) - mur[b] * G[o] + Bb[o];
  }
}

extern "C" void kernel_launch(void* const* d_in, const int* in_sizes, int n_in,
                              void* d_out, int out_size, void* d_ws, size_t ws_size,
                              hipStream_t stream) {
  const float* X       = (const float*)d_in[0];
  const float* centers = (const float*)d_in[1];
  const float* sigmas  = (const float*)d_in[2];
  const float* gamma   = (const float*)d_in[3];
  const float* beta    = (const float*)d_in[4];
  const float* W       = (const float*)d_in[5];
  const float* bias    = (const float*)d_in[6];
  float* out = (float*)d_out;

  char* ws = (char*)d_ws;
  float* scaleA        = (float*)(ws);                    // 131072 B
  float* scB           = (float*)(ws + 131072);           // 131072 B
  float* Cr            = (float*)(ws + 262144);           // 512 B
  float* G             = (float*)(ws + 262656);           // 256 B
  float* Bb            = (float*)(ws + 262912);           // 256 B
  float* Wtail         = (float*)(ws + 263168);           // 32768 B
  float* rstd          = (float*)(ws + 295936);           // 8192 B
  float* mur           = (float*)(ws + 304128);           // 8192 B
  float* frs           = (float*)(ws + 312320);           // 1 MB
  unsigned short* Xbf  = (unsigned short*)(ws + 1360896); // 1 MB
  unsigned short* Bpack= (unsigned short*)(ws + 2409472); // 4 MB
  float* Spart         = (float*)(ws + 6603776);          // 8 MB  (total ~14.3 MB)

  hipLaunchKernelGGL(prep_rules, dim3(NR_), dim3(IN_), 0, stream,
                     centers, sigmas, scaleA, scB, Cr);
  hipLaunchKernelGGL(prep_w, dim3(OUT_), dim3(256), 0, stream,
                     W, gamma, beta, bias, G, Bb, Wtail);
  hipLaunchKernelGGL(prep_bpack, dim3(8, NR_), dim3(64), 0, stream,
                     W, gamma, Bpack);
  hipLaunchKernelGGL(frs_kernel, dim3(B_ / 8), dim3(512), 0, stream,
                     X, scaleA, scB, Cr, frs, rstd, mur, Xbf);
  hipLaunchKernelGGL(gemm_kernel, dim3(16, KSPLIT), dim3(512), 0, stream,
                     Xbf, Bpack, frs, Spart);
  hipLaunchKernelGGL(epilogue_kernel, dim3(B_ / 8), dim3(256), 0, stream,
                     Spart, frs, Wtail, rstd, mur, G, Bb, out);
}

// Round 3
// 117.980 us; speedup vs baseline: 2.6796x; 1.3094x over previous
//
#include <hip/hip_runtime.h>

// PreHTSK fused, MFMA edition v2.
// out[b,o] = rstd*(S + T) - mu*rstd*G[o] + Bb[o]
//   S = sum_r frs[b,r] * sum_i X[b,i]*gamma[r*256+i]*W[o, r*256+i]   (MFMA, A=X in regs)
//   T = sum_r frs[b,r] * Wtail[r][o]                                  (epilogue)
// LN moments closed-form: mu=(Sx+1)/D, E[f^2]=Q*(Sx2+1)/D, Q=sum frs^2.
// v2: prep_w/prep_rules deleted. W read ONCE (prep_pack computes bf16 pack +
// G/Bb partials); frs_kernel computes (x-c)^2*s directly from centers/sigmas.

#define B_    2048
#define IN_   256
#define NR_   128
#define OUT_  64
#define D_    32896
#define XP_   32768
#define KSPLIT 16   // rule-groups -> gemm grid.y ; 8 rules per block

typedef short s16x8 __attribute__((ext_vector_type(8)));
typedef float f32x4 __attribute__((ext_vector_type(4)));

__device__ __forceinline__ unsigned short bfc(float f) {
  union { float f; unsigned int u; } v; v.f = f;
  unsigned int r = (v.u + 0x7fffu + ((v.u >> 16) & 1u)) >> 16;  // RNE
  return (unsigned short)r;
}

// ---------- pack gamma*W into MFMA B-fragment order (bf16) + G/Bb partials
// Bpack[r][kc(8)][ct(4)][lane(64)][j(8)] ; element (k=kc*32+(lane>>4)*8+j, o=ct*16+(lane&15))
// Gpart/Bpart[rb=r*8+kc][o] = sum over this block's 32 d's of W[o,d]*gamma/beta[d]
__global__ __launch_bounds__(64) void prep_pack(const float* __restrict__ W,
                                                const float* __restrict__ gamma,
                                                const float* __restrict__ beta,
                                                unsigned short* __restrict__ Bpack,
                                                float* __restrict__ Gpart,
                                                float* __restrict__ Bpart) {
  int kc = blockIdx.x;   // 0..7
  int r  = blockIdx.y;   // 0..127
  int lane = threadIdx.x;
  int d0 = r * 256 + kc * 32 + (lane >> 4) * 8;
  float4 g0  = *(const float4*)&gamma[d0];
  float4 g1  = *(const float4*)&gamma[d0 + 4];
  float4 be0 = *(const float4*)&beta[d0];
  float4 be1 = *(const float4*)&beta[d0 + 4];
  int rb = r * 8 + kc;
#pragma unroll
  for (int ct = 0; ct < 4; ct++) {
    int o = ct * 16 + (lane & 15);
    const float* wp = &W[(size_t)o * D_ + d0];
    float4 w0 = *(const float4*)wp;
    float4 w1 = *(const float4*)(wp + 4);
    unsigned int u[4];
    u[0] = bfc(w0.x * g0.x) | ((unsigned int)bfc(w0.y * g0.y) << 16);
    u[1] = bfc(w0.z * g0.z) | ((unsigned int)bfc(w0.w * g0.w) << 16);
    u[2] = bfc(w1.x * g1.x) | ((unsigned int)bfc(w1.y * g1.y) << 16);
    u[3] = bfc(w1.z * g1.z) | ((unsigned int)bfc(w1.w * g1.w) << 16);
    *(uint4*)&Bpack[((size_t)(rb * 4 + ct) * 64 + lane) * 8] = make_uint4(u[0], u[1], u[2], u[3]);
    float gs = w0.x*g0.x + w0.y*g0.y + w0.z*g0.z + w0.w*g0.w
             + w1.x*g1.x + w1.y*g1.y + w1.z*g1.z + w1.w*g1.w;
    float bs = w0.x*be0.x + w0.y*be0.y + w0.z*be0.z + w0.w*be0.w
             + w1.x*be1.x + w1.y*be1.y + w1.z*be1.z + w1.w*be1.w;
    gs += __shfl_xor(gs, 16); gs += __shfl_xor(gs, 32);
    bs += __shfl_xor(bs, 16); bs += __shfl_xor(bs, 32);
    if ((lane >> 4) == 0) {
      Gpart[rb * 64 + o] = gs;
      Bpart[rb * 64 + o] = bs;
    }
  }
}

// ---------- finish G/Bb (+tail contribution) and emit Wtail[r][o]
__global__ __launch_bounds__(128) void prep_reduce(const float* __restrict__ W,
                                                   const float* __restrict__ gamma,
                                                   const float* __restrict__ beta,
                                                   const float* __restrict__ bias,
                                                   const float* __restrict__ Gpart,
                                                   const float* __restrict__ Bpart,
                                                   float* __restrict__ G,
                                                   float* __restrict__ Bb,
                                                   float* __restrict__ Wtail) {
  int o = blockIdx.x, t = threadIdx.x;   // 64 blocks x 128 threads
  __shared__ float rg[128], rb_[128];
  float gs = 0.f, bs = 0.f;
  for (int j = t; j < 1024; j += 128) {
    gs += Gpart[j * 64 + o];
    bs += Bpart[j * 64 + o];
  }
  int d = XP_ + t;                        // tail feature r = t
  float wt = W[(size_t)o * D_ + d];
  float gt = wt * gamma[d];
  Wtail[t * OUT_ + o] = gt;
  gs += gt;
  bs += wt * beta[d];
  rg[t] = gs; rb_[t] = bs;
  __syncthreads();
  for (int st = 64; st > 0; st >>= 1) {
    if (t < st) { rg[t] += rg[t + st]; rb_[t] += rb_[t + st]; }
    __syncthreads();
  }
  if (t == 0) { G[o] = rg[0]; Bb[o] = rb_[0] + bias[o]; }
}

// ---------- firing levels + softmax + LN stats + X->bf16  (8 rows/block)
// pre[b,r] = -(1/256) * sum_i (x-c)^2 * s,  s = 0.5/sig^2 + 1e-8  (direct diff^2 form)
__global__ __launch_bounds__(512) void frs_kernel(const float* __restrict__ X,
                                                  const float* __restrict__ centers,
                                                  const float* __restrict__ sigmas,
                                                  float* __restrict__ frs,
                                                  float* __restrict__ rstdO,
                                                  float* __restrict__ murO,
                                                  unsigned short* __restrict__ Xbf) {
  int bt = blockIdx.x;           // 256 blocks
  int tid = threadIdx.x;         // 512
  __shared__ float Xs[8][256];
  __shared__ float pre[4][8][128];
  int b0 = bt * 8;
  {
    int row = tid >> 6, c4 = (tid & 63) * 4;
    float4 x = *(const float4*)&X[(size_t)(b0 + row) * 256 + c4];
    *(float4*)&Xs[row][c4] = x;
    uint2 p;
    p.x = bfc(x.x) | ((unsigned int)bfc(x.y) << 16);
    p.y = bfc(x.z) | ((unsigned int)bfc(x.w) << 16);
    *(uint2*)&Xbf[(size_t)(b0 + row) * 256 + c4] = p;
  }
  __syncthreads();
  int r = tid & 127, h = tid >> 7;   // h = i-quarter
  float acc[8] = {0.f,0.f,0.f,0.f,0.f,0.f,0.f,0.f};
  int i0 = h * 64;
#pragma unroll 4
  for (int i = i0; i < i0 + 64; i++) {
    float sg = sigmas[i * NR_ + r];
    float c  = centers[i * NR_ + r];
    float s  = 0.5f / (sg * sg) + 1e-8f;
#pragma unroll
    for (int row = 0; row < 8; row++) {
      float d = Xs[row][i] - c;
      acc[row] = fmaf(d * s, d, acc[row]);
    }
  }
#pragma unroll
  for (int row = 0; row < 8; row++) pre[h][row][r] = acc[row];
  __syncthreads();
  // wave w handles row w
  int wv = tid >> 6, lane = tid & 63;
  float v0 = pre[0][wv][lane]      + pre[1][wv][lane]      + pre[2][wv][lane]      + pre[3][wv][lane];
  float v1 = pre[0][wv][lane + 64] + pre[1][wv][lane + 64] + pre[2][wv][lane + 64] + pre[3][wv][lane + 64];
  v0 *= -(1.f / 256.f);
  v1 *= -(1.f / 256.f);
  float m = fmaxf(v0, v1);
  for (int st = 32; st; st >>= 1) m = fmaxf(m, __shfl_xor(m, st));
  float e0 = __expf(v0 - m), e1 = __expf(v1 - m);
  float s = e0 + e1;
  for (int st = 32; st; st >>= 1) s += __shfl_xor(s, st);
  float invs = 1.f / s;
  float f0 = e0 * invs, f1 = e1 * invs;
  int b = b0 + wv;
  frs[(size_t)b * 128 + lane]      = f0;
  frs[(size_t)b * 128 + 64 + lane] = f1;
  float q = f0 * f0 + f1 * f1;
  for (int st = 32; st; st >>= 1) q += __shfl_xor(q, st);
  float sx = 0.f, sx2 = 0.f;
#pragma unroll
  for (int j = 0; j < 4; j++) {
    float x = Xs[wv][lane * 4 + j];
    sx += x; sx2 = fmaf(x, x, sx2);
  }
  for (int st = 32; st; st >>= 1) { sx += __shfl_xor(sx, st); sx2 += __shfl_xor(sx2, st); }
  if (lane == 0) {
    float mu  = (sx + 1.f) / (float)D_;
    float msq = q * (sx2 + 1.f) / (float)D_;
    float var = msq - mu * mu;
    float rs  = rsqrtf(var + 1e-5f);
    rstdO[b] = rs;
    murO[b]  = mu * rs;
  }
}

// ---------- MFMA GEMM: grid (16 bt, 16 ks), 512 threads (8 waves)
__global__ __launch_bounds__(512) void gemm_kernel(const unsigned short* __restrict__ Xbf,
                                                   const unsigned short* __restrict__ Bpack,
                                                   const float* __restrict__ frs,
                                                   float* __restrict__ Spart) {
  int bt = blockIdx.x;
  int ks = blockIdx.y;
  int tid = threadIdx.x;
  int lane = tid & 63;
  int w = tid >> 6, wr = w & 3, wc = w >> 2;
  __shared__ unsigned short Blds[2][16384];   // 2 x 32KB
  __shared__ float frs_s[128][9];             // +1 pad: kills 4-way bank conflict in fold

  for (int idx = tid; idx < 128 * 8; idx += 512) {
    int row = idx >> 3, rr = idx & 7;
    frs_s[row][rr] = frs[(size_t)(bt * 128 + row) * 128 + ks * 8 + rr];
  }

  // X fragments in registers, reused across all rules
  s16x8 xf[2][8];
  int browbase = bt * 128 + wr * 32;
#pragma unroll
  for (int rf = 0; rf < 2; rf++) {
    const unsigned short* xp = Xbf + (size_t)(browbase + rf * 16 + (lane & 15)) * 256 + (lane >> 4) * 8;
#pragma unroll
    for (int kc = 0; kc < 8; kc++)
      xf[rf][kc] = *(const s16x8*)(xp + kc * 32);
  }

  const s16x8* bsrc = (const s16x8*)Bpack + (size_t)(ks * 8) * 2048;
  {
    s16x8* dst = (s16x8*)&Blds[0][0];
#pragma unroll
    for (int p = 0; p < 4; p++) dst[tid + p * 512] = bsrc[tid + p * 512];
  }
  __syncthreads();

  f32x4 S00 = {0.f,0.f,0.f,0.f}, S01 = S00, S10 = S00, S11 = S00;
  f32x4 P00 = S00, P01 = S00, P10 = S00, P11 = S00;

  for (int rr = 0; rr < 8; rr++) {
    s16x8 stg0, stg1, stg2, stg3;
    if (rr < 7) {               // T14: issue next-rule loads early
      const s16x8* src = bsrc + (size_t)(rr + 1) * 2048;
      stg0 = src[tid]; stg1 = src[tid + 512]; stg2 = src[tid + 1024]; stg3 = src[tid + 1536];
    }
    const unsigned short* bb = &Blds[rr & 1][0];
#pragma unroll
    for (int kc = 0; kc < 8; kc++) {
      s16x8 bf0 = *(const s16x8*)(bb + (size_t)((kc * 4 + wc * 2 + 0) * 64 + lane) * 8);
      s16x8 bf1 = *(const s16x8*)(bb + (size_t)((kc * 4 + wc * 2 + 1) * 64 + lane) * 8);
      P00 = __builtin_amdgcn_mfma_f32_16x16x32_bf16(xf[0][kc], bf0, P00, 0, 0, 0);
      P01 = __builtin_amdgcn_mfma_f32_16x16x32_bf16(xf[0][kc], bf1, P01, 0, 0, 0);
      P10 = __builtin_amdgcn_mfma_f32_16x16x32_bf16(xf[1][kc], bf0, P10, 0, 0, 0);
      P11 = __builtin_amdgcn_mfma_f32_16x16x32_bf16(xf[1][kc], bf1, P11, 0, 0, 0);
    }
#pragma unroll
    for (int q = 0; q < 4; q++) {
      float fv0 = frs_s[wr * 32 + 0  + (lane >> 4) * 4 + q][rr];
      float fv1 = frs_s[wr * 32 + 16 + (lane >> 4) * 4 + q][rr];
      S00[q] += fv0 * P00[q];  S01[q] += fv0 * P01[q];
      S10[q] += fv1 * P10[q];  S11[q] += fv1 * P11[q];
      P00[q] = 0.f; P01[q] = 0.f; P10[q] = 0.f; P11[q] = 0.f;
    }
    if (rr < 7) {
      s16x8* dst = (s16x8*)&Blds[(rr + 1) & 1][0];
      dst[tid] = stg0; dst[tid + 512] = stg1; dst[tid + 1024] = stg2; dst[tid + 1536] = stg3;
    }
    __syncthreads();
  }

#pragma unroll
  for (int q = 0; q < 4; q++) {
    int row0 = browbase + 0  + (lane >> 4) * 4 + q;
    int row1 = browbase + 16 + (lane >> 4) * 4 + q;
    int o0 = wc * 32 + (lane & 15);
    Spart[((size_t)ks * B_ + row0) * OUT_ + o0]      = S00[q];
    Spart[((size_t)ks * B_ + row0) * OUT_ + o0 + 16] = S01[q];
    Spart[((size_t)ks * B_ + row1) * OUT_ + o0]      = S10[q];
    Spart[((size_t)ks * B_ + row1) * OUT_ + o0 + 16] = S11[q];
  }
}

// ---------- epilogue: sum partials + tail GEMV + LN affine
__global__ __launch_bounds__(256) void epilogue_kernel(const float* __restrict__ Spart,
                                                       const float* __restrict__ frs,
                                                       const float* __restrict__ Wtail,
                                                       const float* __restrict__ rstd,
                                                       const float* __restrict__ mur,
                                                       const float* __restrict__ G,
                                                       const float* __restrict__ Bb,
                                                       float* __restrict__ out) {
  int bt = blockIdx.x;        // 256 blocks, 8 rows each
  int tid = threadIdx.x;
  __shared__ float Wt[128 * 64];
  __shared__ float fr_s[8][128];
  for (int idx = tid; idx < 128 * 64; idx += 256) Wt[idx] = Wtail[idx];
  for (int idx = tid; idx < 8 * 128; idx += 256) {
    int row = idx >> 7, r = idx & 127;
    fr_s[row][r] = frs[(size_t)(bt * 8 + row) * 128 + r];
  }
  __syncthreads();
  int o = tid & 63, rg = tid >> 6;
  for (int rw = rg; rw < 8; rw += 4) {
    int b = bt * 8 + rw;
    float s = 0.f;
#pragma unroll
    for (int ksi = 0; ksi < KSPLIT; ksi++)
      s += Spart[((size_t)ksi * B_ + b) * OUT_ + o];
    float t = 0.f;
#pragma unroll 8
    for (int r = 0; r < 128; r++)
      t = fmaf(fr_s[rw][r], Wt[r * 64 + o], t);
    out[(size_t)b * OUT_ + o] = rstd[b] * (s + t) - mur[b] * G[o] + Bb[o];
  }
}

extern "C" void kernel_launch(void* const* d_in, const int* in_sizes, int n_in,
                              void* d_out, int out_size, void* d_ws, size_t ws_size,
                              hipStream_t stream) {
  const float* X       = (const float*)d_in[0];
  const float* centers = (const float*)d_in[1];
  const float* sigmas  = (const float*)d_in[2];
  const float* gamma   = (const float*)d_in[3];
  const float* beta    = (const float*)d_in[4];
  const float* W       = (const float*)d_in[5];
  const float* bias    = (const float*)d_in[6];
  float* out = (float*)d_out;

  char* ws = (char*)d_ws;
  float* G             = (float*)(ws);                     // 256 B
  float* Bb            = (float*)(ws + 256);               // 256 B
  float* Wtail         = (float*)(ws + 512);               // 32768 B
  float* rstd          = (float*)(ws + 33280);             // 8192 B
  float* mur           = (float*)(ws + 41472);             // 8192 B
  float* frs           = (float*)(ws + 49664);             // 1 MB
  unsigned short* Xbf  = (unsigned short*)(ws + 1098240);  // 1 MB
  unsigned short* Bpack= (unsigned short*)(ws + 2146816);  // 4 MB
  float* Spart         = (float*)(ws + 6341120);           // 8 MB
  float* Gpart         = (float*)(ws + 14729728);          // 256 KB
  float* Bpart         = (float*)(ws + 14991872);          // 256 KB  (total ~14.6 MB)

  hipLaunchKernelGGL(prep_pack, dim3(8, NR_), dim3(64), 0, stream,
                     W, gamma, beta, Bpack, Gpart, Bpart);
  hipLaunchKernelGGL(prep_reduce, dim3(OUT_), dim3(128), 0, stream,
                     W, gamma, beta, bias, Gpart, Bpart, G, Bb, Wtail);
  hipLaunchKernelGGL(frs_kernel, dim3(B_ / 8), dim3(512), 0, stream,
                     X, centers, sigmas, frs, rstd, mur, Xbf);
  hipLaunchKernelGGL(gemm_kernel, dim3(16, KSPLIT), dim3(512), 0, stream,
                     Xbf, Bpack, frs, Spart);
  hipLaunchKernelGGL(epilogue_kernel, dim3(B_ / 8), dim3(256), 0, stream,
                     Spart, frs, Wtail, rstd, mur, G, Bb, out);
}